// Round 6
// baseline (978.170 us; speedup 1.0000x reference)
//
#include <hip/hip_runtime.h>
#include <hip/hip_bf16.h>
#include <stdint.h>

// ---------------- problem constants ----------------
#define LL      3
#define NNODES  4000
#define NRELS   200
#define VV      20
#define EMB     128
#define HIDD    128
#define OUTD    100
#define WS_N    50000
#define WS_E    800000
#define BV      32
#define DECAYF  0.03f
#define AK      4032   // K padded to multiple of 64 (63*64) for BK=64 glds staging
#define ZSTRIDE ((long)LL*640*4000)   // one split-K partial of z (bf16)

typedef __bf16 bf16x8 __attribute__((ext_vector_type(8)));
typedef __bf16 bf16x4 __attribute__((ext_vector_type(4)));
typedef __bf16 bf16x2 __attribute__((ext_vector_type(2)));
typedef float  f32x4  __attribute__((ext_vector_type(4)));

// async global->LDS, 16B per lane; LDS dest = wave-uniform base + lane*16 (m97/m104)
__device__ __forceinline__ void glds16(const __bf16* g, __bf16* l) {
    __builtin_amdgcn_global_load_lds((const __attribute__((address_space(1))) void*)g,
                                     (__attribute__((address_space(3))) void*)l, 16, 0, 0);
}

// ---------------- f32 -> bf16 conversion, zero-padded K tail; visit + alpha fused ----------------
__global__ __launch_bounds__(256) void k_cvt2(const float* __restrict__ visit,
                                              const float* __restrict__ alpha_w,
                                              __bf16* __restrict__ visit_bf,
                                              __bf16* __restrict__ alpha_bf) {
    long bid = blockIdx.x;
    const float* ip; __bf16* op;
    if (bid < BV*VV) { ip = visit + bid*4000; op = visit_bf + bid*AK; }
    else             { long r = bid - BV*VV; ip = alpha_w + r*4000; op = alpha_bf + r*AK; }
    int t = threadIdx.x;
    if (t < 250) {
        const float4* p4 = (const float4*)ip + t*4;
        float4 f0 = p4[0], f1 = p4[1], f2 = p4[2], f3 = p4[3];
        bf16x8 h0, h1;
        h0[0]=(__bf16)f0.x; h0[1]=(__bf16)f0.y; h0[2]=(__bf16)f0.z; h0[3]=(__bf16)f0.w;
        h0[4]=(__bf16)f1.x; h0[5]=(__bf16)f1.y; h0[6]=(__bf16)f1.z; h0[7]=(__bf16)f1.w;
        h1[0]=(__bf16)f2.x; h1[1]=(__bf16)f2.y; h1[2]=(__bf16)f2.z; h1[3]=(__bf16)f2.w;
        h1[4]=(__bf16)f3.x; h1[5]=(__bf16)f3.y; h1[6]=(__bf16)f3.z; h1[7]=(__bf16)f3.w;
        ((bf16x8*)op)[t*2]   = h0;
        ((bf16x8*)op)[t*2+1] = h1;
    } else if (t < 254) {
        bf16x8 zz;
        #pragma unroll
        for (int j = 0; j < 8; j++) zz[j] = (__bf16)0.f;
        ((bf16x8*)op)[500 + (t - 250)] = zz;
    }
}

// ---------------- alpha GEMM: z[l,row,col] = visit[row,:] . alpha_w[l][col,:] ----------------
// bf16 in (stride AK), BK=64 glds16 staging, XOR-swizzled LDS (0 bank conflicts, R5),
// XCD-grouped swizzle (R3), split-K=4 with bf16 partial stores (R6: TLP 960->1920 blocks).
__global__ __launch_bounds__(256)
void gemm_alpha(const __bf16* __restrict__ visit_bf, const __bf16* __restrict__ alpha_bf,
                __bf16* __restrict__ zpart)
{
    __shared__ __bf16 Ah[128*64];   // granule g of row r at r*64 + (g^(r&7))*8
    __shared__ __bf16 Bh[128*64];

    const int id   = blockIdx.x;      // 0..1919
    const int xcd  = id & 7;
    const int slot = id >> 3;         // 0..239
    const int mi   = slot % 5;        // 0..4
    const int gix  = slot / 5;        // 0..47
    const int g    = xcd * 48 + gix;  // 0..383
    const int ni   = g & 31;          // 0..31
    const int lkh  = g >> 5;          // 0..11
    const int l    = lkh >> 2;        // 0..2
    const int kh   = lkh & 3;         // 0..3

    const __bf16* Ag = visit_bf;
    const __bf16* Bg = alpha_bf + (long)l * NNODES * AK;
    __bf16*       Cg = zpart + (long)kh * ZSTRIDE + (long)l * 640 * 4000;
    const int m0 = mi * 128;
    const int n0 = ni * 128;
    const int k0 = kh * 1024;
    const int k1 = (kh == 3) ? AK : (k0 + 1024);

    const int tid = threadIdx.x;
    const int wv  = tid >> 6;
    const int ln  = tid & 63;
    const int srow = ln >> 3;
    const int gsl  = (ln & 7) ^ srow;

    const __bf16* aA = Ag + (long)(m0 + wv*8 + srow) * AK + gsl*8;
    const __bf16* bB[4];
    #pragma unroll
    for (int t = 0; t < 4; t++) {
        int br = n0 + wv*8 + srow + t*32;
        if (br > NNODES-1) br = NNODES-1;      // clamp (cols>=4000 masked at store)
        bB[t] = Bg + (long)br * AK + gsl*8;
    }

    const int wm = (wv & 1) * 64;
    const int wn = (wv >> 1) * 64;
    const int lr = ln & 15;
    const int kq = ln >> 4;
    const int sw0 = lr & 7;

    f32x4 acc[4][4];
    #pragma unroll
    for (int i = 0; i < 4; i++)
        #pragma unroll
        for (int j = 0; j < 4; j++)
            acc[i][j] = (f32x4){0.f, 0.f, 0.f, 0.f};

    for (int kb = k0; kb < k1; kb += 64) {
        #pragma unroll
        for (int t = 0; t < 4; t++) {
            glds16(aA + (long)t*32*AK + kb, &Ah[(t*4 + wv) * 512]);
            glds16(bB[t] + kb,              &Bh[(t*4 + wv) * 512]);
        }
        __syncthreads();
        #pragma unroll
        for (int ks = 0; ks < 2; ks++) {
            const int sg = ((ks*4 + kq) ^ sw0) * 8;
            bf16x8 af[4], bfr[4];
            #pragma unroll
            for (int i = 0; i < 4; i++) {
                af[i]  = *(const bf16x8*)&Ah[(wm + i*16 + lr)*64 + sg];
                bfr[i] = *(const bf16x8*)&Bh[(wn + i*16 + lr)*64 + sg];
            }
            #pragma unroll
            for (int i = 0; i < 4; i++)
                #pragma unroll
                for (int j = 0; j < 4; j++)
                    acc[i][j] = __builtin_amdgcn_mfma_f32_16x16x32_bf16(af[i], bfr[j], acc[i][j], 0, 0, 0);
        }
        __syncthreads();
    }

    // C/D layout col=lane&15, row=(lane>>4)*4+reg (m89/m91-verified)
    #pragma unroll
    for (int i = 0; i < 4; i++) {
        const int row_b = m0 + wm + i*16 + kq*4;   // < 640 always
        #pragma unroll
        for (int j = 0; j < 4; j++) {
            const int col = n0 + wn + j*16 + lr;
            if (col < NNODES) {
                #pragma unroll
                for (int r = 0; r < 4; r++)
                    Cg[(long)(row_b + r)*4000 + col] = (__bf16)acc[i][j][r];
            }
        }
    }
}

// ---------------- generic small GEMM (C = A * B^T), split-bf16 for ~f32 accuracy ----------------
#define BM 128
#define BN 128
#define BKG 32
#define LSTR 40

template<int SPLIT>
__device__ __forceinline__ void stage_tile(const float* __restrict__ G, int rows, int Kdim,
                                           int r0, int kb, int k1, __bf16* Sh, __bf16* Sl, int tid)
{
    const int sr  = tid >> 1;
    const int skc = (tid & 1) * 16;
    const int gr  = r0 + sr;
    const int gk  = kb + skc;
    float va[16];
    if (gr < rows && gk + 16 <= k1) {
        const float4* p4 = (const float4*)(G + (long)gr * Kdim + gk);
        #pragma unroll
        for (int q = 0; q < 4; q++) {
            float4 f = p4[q];
            va[4*q+0] = f.x; va[4*q+1] = f.y; va[4*q+2] = f.z; va[4*q+3] = f.w;
        }
    } else {
        #pragma unroll
        for (int j = 0; j < 16; j++) {
            int kk = gk + j;
            va[j] = (gr < rows && kk < k1) ? G[(long)gr * Kdim + kk] : 0.0f;
        }
    }
    bf16x8 h[2], lo[2];
    #pragma unroll
    for (int half = 0; half < 2; half++) {
        #pragma unroll
        for (int j = 0; j < 8; j++) {
            float v = va[half*8 + j];
            __bf16 hi = (__bf16)v;
            h[half][j]  = hi;
            lo[half][j] = (__bf16)(v - (float)hi);
        }
    }
    *(bf16x8*)&Sh[sr*LSTR + skc]     = h[0];
    *(bf16x8*)&Sh[sr*LSTR + skc + 8] = h[1];
    if (SPLIT) {
        *(bf16x8*)&Sl[sr*LSTR + skc]     = lo[0];
        *(bf16x8*)&Sl[sr*LSTR + skc + 8] = lo[1];
    }
}

template<int SPLIT, int RELU, int BIAS, int WRITEB>
__global__ __launch_bounds__(256)
void gemm_bt(const float* __restrict__ Ag, const float* __restrict__ Bg,
             float* __restrict__ Cg, const float* __restrict__ bias,
             __bf16* __restrict__ Xb, int M, int N, int K)
{
    __shared__ __bf16 Ah[BM*LSTR];
    __shared__ __bf16 Bh[BN*LSTR];
    __shared__ __bf16 Alo[SPLIT ? BM*LSTR : 1];
    __shared__ __bf16 Blo[SPLIT ? BN*LSTR : 1];

    const int tid = threadIdx.x;
    const int m0 = blockIdx.x * BM;
    const int n0 = blockIdx.y * BN;

    const int wave = tid >> 6;
    const int lane = tid & 63;
    const int wm = (wave & 1) * 64;
    const int wn = (wave >> 1) * 64;
    const int lr = lane & 15;
    const int kq = lane >> 4;

    f32x4 acc[4][4];
    #pragma unroll
    for (int i = 0; i < 4; i++)
        #pragma unroll
        for (int j = 0; j < 4; j++)
            acc[i][j] = (f32x4){0.f, 0.f, 0.f, 0.f};

    for (int kb = 0; kb < K; kb += BKG) {
        stage_tile<SPLIT>(Ag, M, K, m0, kb, K, Ah, Alo, tid);
        stage_tile<SPLIT>(Bg, N, K, n0, kb, K, Bh, Blo, tid);
        __syncthreads();

        bf16x8 af[4], bfr[4];
        #pragma unroll
        for (int i = 0; i < 4; i++) {
            af[i]  = *(const bf16x8*)&Ah[(wm + i*16 + lr)*LSTR + kq*8];
            bfr[i] = *(const bf16x8*)&Bh[(wn + i*16 + lr)*LSTR + kq*8];
        }
        #pragma unroll
        for (int i = 0; i < 4; i++)
            #pragma unroll
            for (int j = 0; j < 4; j++)
                acc[i][j] = __builtin_amdgcn_mfma_f32_16x16x32_bf16(af[i], bfr[j], acc[i][j], 0, 0, 0);

        if (SPLIT) {
            bf16x8 al[4], bl[4];
            #pragma unroll
            for (int i = 0; i < 4; i++) {
                al[i] = *(const bf16x8*)&Alo[(wm + i*16 + lr)*LSTR + kq*8];
                bl[i] = *(const bf16x8*)&Blo[(wn + i*16 + lr)*LSTR + kq*8];
            }
            #pragma unroll
            for (int i = 0; i < 4; i++)
                #pragma unroll
                for (int j = 0; j < 4; j++) {
                    acc[i][j] = __builtin_amdgcn_mfma_f32_16x16x32_bf16(af[i], bl[j], acc[i][j], 0, 0, 0);
                    acc[i][j] = __builtin_amdgcn_mfma_f32_16x16x32_bf16(al[i], bfr[j], acc[i][j], 0, 0, 0);
                }
        }
        __syncthreads();
    }

    #pragma unroll
    for (int i = 0; i < 4; i++) {
        const int row_b = m0 + wm + i*16 + kq*4;
        #pragma unroll
        for (int j = 0; j < 4; j++) {
            const int col = n0 + wn + j*16 + lr;
            if (col < N) {
                #pragma unroll
                for (int r = 0; r < 4; r++) {
                    const int row = row_b + r;
                    if (row < M) {
                        float v = acc[i][j][r];
                        if (BIAS) v += bias[col];
                        if (RELU) v = fmaxf(v, 0.0f);
                        Cg[(long)row*N + col] = v;
                        if (WRITEB) Xb[(long)row*N + col] = (__bf16)v;
                    }
                }
            }
        }
    }
}

// ---------------- CSR build ----------------
__global__ void k_count(const int* __restrict__ dst, int* __restrict__ deg) {
    int e = blockIdx.x*256 + threadIdx.x;
    if (e < WS_E) atomicAdd(&deg[dst[e]], 1);
}

__global__ __launch_bounds__(1024) void k_scan(const int* __restrict__ deg, int* __restrict__ offs,
                                               int* __restrict__ cursor, int n) {
    __shared__ int part[1024];
    int t = threadIdx.x;
    int chunk = (n + 1023) / 1024;
    int s0 = t * chunk;
    int s1 = min(s0 + chunk, n);
    int s = 0;
    for (int i = s0; i < s1; i++) s += deg[i];
    part[t] = s; __syncthreads();
    for (int off = 1; off < 1024; off <<= 1) {
        int v = part[t];
        if (t >= off) v += part[t - off];
        __syncthreads();
        part[t] = v;
        __syncthreads();
    }
    int pre = (t == 0) ? 0 : part[t - 1];
    for (int i = s0; i < s1; i++) { offs[i] = pre; cursor[i] = pre; pre += deg[i]; }
    if (t == 1023) offs[n] = pre;
}

__global__ void k_fill(const int* __restrict__ dst, const int* __restrict__ src,
                       const int* __restrict__ rel, int* __restrict__ cursor,
                       int2* __restrict__ sr) {
    int e = blockIdx.x*256 + threadIdx.x;
    if (e < WS_E) {
        int d = dst[e];
        int p = atomicAdd(&cursor[d], 1);
        sr[p] = make_int2(src[e], rel[e]);
    }
}

// ---------------- small precompute kernels ----------------
__global__ __launch_bounds__(128) void k_relmsg(const float* __restrict__ Wrel, const float* __restrict__ wr_w,
                                                const float* __restrict__ wr_b, __bf16* __restrict__ relmsg) {
    int l = blockIdx.x / NRELS;
    int r = blockIdx.x % NRELS;
    int o = threadIdx.x;
    float wv = Wrel[r*HIDD + o];
    __shared__ float red[128];
    red[o] = wv * wr_w[l*HIDD + o];
    __syncthreads();
    for (int s = 64; s > 0; s >>= 1) {
        if (o < s) red[o] += red[o + s];
        __syncthreads();
    }
    float wrel = red[0] + wr_b[l];
    relmsg[((long)l*NRELS + r)*HIDD + o] = (__bf16)(wrel * wv);
}

// x init + bf16 shadow + per-layer node attention gather (fused)
__global__ void k_xinit(const float* __restrict__ Wnode, const int* __restrict__ nid,
                        const int* __restrict__ batch, const float* __restrict__ attn,
                        float* __restrict__ x, __bf16* __restrict__ xb, float* __restrict__ an) {
    int t = blockIdx.x*256 + threadIdx.x;
    if (t >= WS_N*32) return;
    int i = t >> 5;
    int d = t & 31;
    int n = nid[i];
    float4 v = ((const float4*)Wnode)[n*32 + d];
    ((float4*)x)[i*32 + d] = v;
    bf16x4 b;
    b[0] = (__bf16)v.x; b[1] = (__bf16)v.y; b[2] = (__bf16)v.z; b[3] = (__bf16)v.w;
    ((bf16x4*)xb)[i*32 + d] = b;
    if (d < LL) an[(long)d*WS_N + i] = attn[((long)d*BV + batch[i]) * NNODES + n];
}

__global__ __launch_bounds__(256) void k_beta(const float* __restrict__ visit, const float* __restrict__ beta_w,
                                              const float* __restrict__ beta_b, float* __restrict__ beta) {
    int id = blockIdx.x;
    int l = id / (BV*VV);
    int rem = id % (BV*VV);
    int b = rem / VV;
    int v = rem % VV;
    const float* row = visit + ((long)b*VV + v) * NNODES;
    const float* wr  = beta_w + (long)l * NNODES;
    float s = 0.f;
    for (int n = threadIdx.x; n < NNODES; n += 256) s += row[n] * wr[n];
    __shared__ float red[256];
    red[threadIdx.x] = s; __syncthreads();
    for (int o = 128; o > 0; o >>= 1) {
        if (threadIdx.x < o) red[threadIdx.x] += red[threadIdx.x + o];
        __syncthreads();
    }
    if (threadIdx.x == 0) {
        float lam = __expf(DECAYF * (float)(VV - v));
        beta[id] = tanhf(red[0] + beta_b[l]) * lam;
    }
}

// softmax over v + beta-weighted pool; sums the 4 bf16 split-K partials inline
__global__ __launch_bounds__(256) void k_attnpool(const __bf16* __restrict__ zpart,
                                                  const float* __restrict__ beta, float* __restrict__ attn) {
    int m = blockIdx.x*256 + threadIdx.x;
    int b = blockIdx.y;
    int l = blockIdx.z;
    if (m >= NNODES) return;
    const __bf16* zp = zpart + ((long)l*640 + b*VV) * 4000 + m;
    const float* bet = beta + (l*BV + b) * VV;
    float zv[VV];
    float mx = -1e30f;
    #pragma unroll
    for (int v = 0; v < VV; v++) {
        long o = (long)v * 4000;
        float s = (float)zp[o] + (float)zp[ZSTRIDE + o] + (float)zp[2*ZSTRIDE + o] + (float)zp[3*ZSTRIDE + o];
        zv[v] = s;
        mx = fmaxf(mx, s);
    }
    float s = 0.f, ws = 0.f;
    #pragma unroll
    for (int v = 0; v < VV; v++) {
        float e = __expf(zv[v] - mx);
        s += e;
        ws += e * bet[v];
    }
    attn[((long)l*BV + b) * NNODES + m] = ws / s;
}

// ---------------- message + aggregate: 2 waves per dst node (even/odd edges), LDS combine ----------------
__global__ __launch_bounds__(256) void k_agg(const float* __restrict__ x, const __bf16* __restrict__ xb,
                                             const float* __restrict__ an,
                                             const __bf16* __restrict__ relmsg_l, const int* __restrict__ offs,
                                             const int2* __restrict__ sr,
                                             float* __restrict__ outb) {
    const int lane = threadIdx.x & 63;
    const int half = (threadIdx.x >> 6) & 1;
    const int nl   = threadIdx.x >> 7;            // 0..1
    const int node = blockIdx.x*2 + nl;
    __shared__ float2 part[2][64];
    const bf16x2* xb2 = (const bf16x2*)xb;
    const bf16x2* rm2 = (const bf16x2*)relmsg_l;
    float2 acc = {0.f, 0.f};
    int e0 = 0, e1 = 0;
    if (node < WS_N) { e0 = offs[node]; e1 = offs[node + 1]; }
    int e = e0 + half;
    for (; e + 6 < e1; e += 8) {     // 4 edges (stride 2) per iter
        int2 p0 = sr[e], p1 = sr[e+2], p2 = sr[e+4], p3 = sr[e+6];
        float a0 = an[p0.x], a1 = an[p1.x], a2 = an[p2.x], a3 = an[p3.x];
        bf16x2 g0 = xb2[p0.x*64 + lane], g1 = xb2[p1.x*64 + lane];
        bf16x2 g2 = xb2[p2.x*64 + lane], g3 = xb2[p3.x*64 + lane];
        bf16x2 m0 = rm2[p0.y*64 + lane], m1 = rm2[p1.y*64 + lane];
        bf16x2 m2 = rm2[p2.y*64 + lane], m3 = rm2[p3.y*64 + lane];
        acc.x += fmaxf((float)g0[0]*a0 + (float)m0[0], 0.f) + fmaxf((float)g1[0]*a1 + (float)m1[0], 0.f)
               + fmaxf((float)g2[0]*a2 + (float)m2[0], 0.f) + fmaxf((float)g3[0]*a3 + (float)m3[0], 0.f);
        acc.y += fmaxf((float)g0[1]*a0 + (float)m0[1], 0.f) + fmaxf((float)g1[1]*a1 + (float)m1[1], 0.f)
               + fmaxf((float)g2[1]*a2 + (float)m2[1], 0.f) + fmaxf((float)g3[1]*a3 + (float)m3[1], 0.f);
    }
    for (; e < e1; e += 2) {
        int2 pa = sr[e];
        float aa = an[pa.x];
        bf16x2 ga = xb2[pa.x*64 + lane];
        bf16x2 va = rm2[pa.y*64 + lane];
        acc.x += fmaxf((float)ga[0]*aa + (float)va[0], 0.f);
        acc.y += fmaxf((float)ga[1]*aa + (float)va[1], 0.f);
    }
    if (half) part[nl][lane] = acc;
    __syncthreads();
    if (!half && node < WS_N) {
        float2 po = part[nl][lane];
        float2 xo = ((const float2*)x)[node*64 + lane];
        acc.x += po.x + xo.x;
        acc.y += po.y + xo.y;
        ((float2*)outb)[node*64 + lane] = acc;
    }
}

// ---------------- pooling partials ----------------
__global__ __launch_bounds__(256) void k_pool_partial(const float* __restrict__ x,
                                                      const int* __restrict__ batch,
                                                      float* __restrict__ xgsum) {
    int r0 = blockIdx.x * 128;
    int d = threadIdx.x & 127;
    int rofs = threadIdx.x >> 7;
    int r1 = min(r0 + 128, WS_N);
    float acc = 0.f;
    int curb = -1;
    for (int i = r0 + rofs; i < r1; i += 2) {
        int b = batch[i];
        if (b != curb) {
            if (curb >= 0) atomicAdd(&xgsum[curb*HIDD + d], acc);
            acc = 0.f; curb = b;
        }
        acc += x[(long)i*HIDD + d];
    }
    if (curb >= 0) atomicAdd(&xgsum[curb*HIDD + d], acc);
}

__global__ __launch_bounds__(128) void k_ehrpool(const float* __restrict__ ehr,
                                                 const float* __restrict__ node_emb,
                                                 float* __restrict__ xnsum, float* __restrict__ esum) {
    int b = blockIdx.y;
    int c = blockIdx.x;
    int d = threadIdx.x;
    int n0 = c * (NNODES/16), n1 = n0 + (NNODES/16);
    float acc = 0.f;
    for (int n = n0; n < n1; n++) {
        acc += ehr[b*NNODES + n] * node_emb[(long)n*HIDD + d];
    }
    atomicAdd(&xnsum[b*HIDD + d], acc);
    float s = 0.f;
    for (int n = n0 + d; n < n1; n += 128) s += ehr[b*NNODES + n];
    __shared__ float red[128];
    red[d] = s; __syncthreads();
    for (int o = 64; o > 0; o >>= 1) {
        if (d < o) red[d] += red[d + o];
        __syncthreads();
    }
    if (d == 0) atomicAdd(&esum[b], red[0]);
}

// fused head: batch-count (binary search) + mean + x_node linear + concat + mlp
__global__ __launch_bounds__(128) void k_head(const float* __restrict__ xgsum,
                                              const float* __restrict__ xnsum,
                                              const float* __restrict__ esum,
                                              const int* __restrict__ batch,
                                              const float* __restrict__ lin_w, const float* __restrict__ lin_b,
                                              const float* __restrict__ mlp_w, const float* __restrict__ mlp_b,
                                              float* __restrict__ out) {
    int b = blockIdx.x;
    int d = threadIdx.x;
    int lo = 0, hi = WS_N;
    while (lo < hi) { int mid = (lo + hi) >> 1; if (batch[mid] < b) lo = mid + 1; else hi = mid; }
    int s0 = lo;
    lo = 0; hi = WS_N;
    while (lo < hi) { int mid = (lo + hi) >> 1; if (batch[mid] < b + 1) lo = mid + 1; else hi = mid; }
    int cnt = max(lo - s0, 1);
    __shared__ float t1[128];
    __shared__ float cat[2*HIDD];
    t1[d]  = xnsum[b*HIDD + d] / esum[b];
    cat[d] = xgsum[b*HIDD + d] / (float)cnt;
    __syncthreads();
    float o2 = lin_b[d];
    for (int k2 = 0; k2 < HIDD; k2++) o2 += t1[k2] * lin_w[d*HIDD + k2];
    cat[HIDD + d] = o2;
    __syncthreads();
    if (d < OUTD) {
        float a = mlp_b[d];
        for (int j = 0; j < 2*HIDD; j++) a += cat[j] * mlp_w[d*2*HIDD + j];
        out[b*OUTD + d] = a;
    }
}

// ---------------- launcher ----------------
extern "C" void kernel_launch(void* const* d_in, const int* in_sizes, int n_in,
                              void* d_out, int out_size, void* d_ws, size_t ws_size,
                              hipStream_t stream)
{
    const float* node_emb = (const float*)d_in[0];
    const float* rel_emb  = (const float*)d_in[1];
    const float* lin_w    = (const float*)d_in[2];
    const float* lin_b    = (const float*)d_in[3];
    const float* alpha_w  = (const float*)d_in[4];
    // d_in[5] alpha_b: shift-invariant under softmax over v -> unused
    const float* beta_w   = (const float*)d_in[6];
    const float* beta_b   = (const float*)d_in[7];
    const float* wr_w     = (const float*)d_in[8];
    const float* wr_b     = (const float*)d_in[9];
    const float* conv_w   = (const float*)d_in[10];
    const float* conv_b   = (const float*)d_in[11];
    const float* mlp_w    = (const float*)d_in[12];
    const float* mlp_b    = (const float*)d_in[13];
    const float* visit    = (const float*)d_in[14];
    const float* ehr      = (const float*)d_in[15];
    const int* node_ids   = (const int*)d_in[16];
    const int* rel_ids    = (const int*)d_in[17];
    const int* ei         = (const int*)d_in[18];
    const int* batch      = (const int*)d_in[19];
    const int* esrc = ei;
    const int* edst = ei + WS_E;
    float* out = (float*)d_out;

    char* p = (char*)d_ws;
    auto take = [&](size_t bytes) -> char* {
        char* q = p;
        p += (bytes + 255) & ~(size_t)255;
        return q;
    };
    __bf16* zpart    = (__bf16*)take((size_t)4*ZSTRIDE*2);        // 61.4 MB: 4 bf16 split-K partials (aggbuf later)
    __bf16* visit_bf = (__bf16*)take((size_t)(BV*VV)*AK*2);       // 5.2 MB
    char*   big      = take((size_t)LL*NNODES*AK*2);              // 96.8 MB: alpha_bf, then carved
    float* betab  = (float*)take((size_t)LL*BV*VV*4);
    float* xgsum  = (float*)take((size_t)BV*HIDD*4);
    float* xnsum  = (float*)take((size_t)BV*HIDD*4);
    float* esum   = (float*)take((size_t)BV*4);
    size_t small_zero_bytes = (size_t)((char*)(esum + BV) - (char*)xgsum);
    int* deg      = (int*)take((size_t)WS_N*4);
    int* offs     = (int*)take((size_t)(WS_N+1)*4);
    int* cursor   = (int*)take((size_t)WS_N*4);
    if ((size_t)(p - (char*)d_ws) > ws_size) return;  // ws too small: leave output poisoned (visible failure)

    // alpha_bf occupies `big` during cvt+gemm_alpha; afterwards carved (stream-ordered -> safe):
    __bf16* alpha_bf = (__bf16*)big;
    char* q = big;
    auto carve = [&](size_t bytes) -> char* {
        char* r = q;
        q += (bytes + 255) & ~(size_t)255;
        return r;
    };
    float*  x      = (float*)carve((size_t)WS_N*HIDD*4);     // 25.6 MB
    __bf16* xb     = (__bf16*)carve((size_t)WS_N*HIDD*2);    // 12.8 MB
    int2*   sr     = (int2*)carve((size_t)WS_E*8);           // 6.4 MB
    float*  attn   = (float*)carve((size_t)LL*BV*NNODES*4);  // 1.5 MB (written by attnpool AFTER gemm_alpha)
    float*  attnnd = (float*)carve((size_t)LL*WS_N*4);       // 0.6 MB
    float*  Wnode  = (float*)carve((size_t)NNODES*HIDD*4);   // 2.0 MB
    float*  Wrel   = (float*)carve((size_t)NRELS*HIDD*4);
    __bf16* relmsg = (__bf16*)carve((size_t)LL*NRELS*HIDD*2);
    float*  aggbuf = (float*)zpart;                          // zpart dead after attnpool

    (void)hipMemsetAsync(deg, 0, (size_t)WS_N*4, stream);
    (void)hipMemsetAsync(xgsum, 0, small_zero_bytes, stream);

    // ---- phase 1: alpha attention ----
    k_cvt2<<<dim3(BV*VV + LL*NNODES), 256, 0, stream>>>(visit, alpha_w, visit_bf, alpha_bf);
    gemm_alpha<<<dim3(1920), 256, 0, stream>>>(visit_bf, alpha_bf, zpart);
    k_beta<<<dim3(LL*BV*VV), 256, 0, stream>>>(visit, beta_w, beta_b, betab);
    k_attnpool<<<dim3((NNODES+255)/256, BV, LL), 256, 0, stream>>>(zpart, betab, attn);

    // ---- phase 2: graph features (carved from the now-dead alpha_bf region) ----
    k_count<<<dim3((WS_E+255)/256), 256, 0, stream>>>(edst, deg);
    k_scan<<<1, 1024, 0, stream>>>(deg, offs, cursor, WS_N);
    k_fill<<<dim3((WS_E+255)/256), 256, 0, stream>>>(edst, esrc, rel_ids, cursor, sr);

    gemm_bt<1,0,1,0><<<dim3((NNODES+BM-1)/BM, 1, 1), 256, 0, stream>>>(
        node_emb, lin_w, Wnode, lin_b, nullptr, NNODES, HIDD, HIDD);
    gemm_bt<1,0,1,0><<<dim3((NRELS+BM-1)/BM, 1, 1), 256, 0, stream>>>(
        rel_emb, lin_w, Wrel, lin_b, nullptr, NRELS, HIDD, HIDD);
    k_relmsg<<<dim3(LL*NRELS), 128, 0, stream>>>(Wrel, wr_w, wr_b, relmsg);
    k_xinit<<<dim3((WS_N*32+255)/256), 256, 0, stream>>>(Wnode, node_ids, batch, attn, x, xb, attnnd);

    // ---- phase 3: GNN layers ----
    for (int l = 0; l < LL; l++) {
        k_agg<<<dim3((WS_N+1)/2), 256, 0, stream>>>(
            x, xb, attnnd + (size_t)l*WS_N, relmsg + (size_t)l*NRELS*HIDD, offs, sr, aggbuf);
        gemm_bt<1,1,1,1><<<dim3((WS_N+BM-1)/BM, 1, 1), 256, 0, stream>>>(
            aggbuf, conv_w + (size_t)l*HIDD*HIDD, x, conv_b + (size_t)l*HIDD, xb,
            WS_N, HIDD, HIDD);
    }

    // ---- phase 4: pooling + head ----
    k_pool_partial<<<dim3((WS_N+127)/128), 256, 0, stream>>>(x, batch, xgsum);
    k_ehrpool<<<dim3(16, BV), 128, 0, stream>>>(ehr, node_emb, xnsum, esum);
    k_head<<<BV, 128, 0, stream>>>(xgsum, xnsum, esum, batch, lin_w, lin_b, mlp_w, mlp_b, out);
}

// Round 7
// 845.137 us; speedup vs baseline: 1.1574x; 1.1574x over previous
//
#include <hip/hip_runtime.h>
#include <hip/hip_bf16.h>
#include <stdint.h>

// ---------------- problem constants ----------------
#define LL      3
#define NNODES  4000
#define NRELS   200
#define VV      20
#define EMB     128
#define HIDD    128
#define OUTD    100
#define WS_N    50000
#define WS_E    800000
#define BV      32
#define DECAYF  0.03f
#define AK      4032   // K padded to multiple of 64 for BK=64 glds staging
#define ZSTRIDE ((long)LL*640*4000)   // one split-K partial of z (bf16)
#define SCAN_NB 196    // ceil(WS_N/256)

typedef __bf16 bf16x8 __attribute__((ext_vector_type(8)));
typedef __bf16 bf16x4 __attribute__((ext_vector_type(4)));
typedef __bf16 bf16x2 __attribute__((ext_vector_type(2)));
typedef float  f32x4  __attribute__((ext_vector_type(4)));

// async global->LDS, 16B per lane; LDS dest = wave-uniform base + lane*16 (m97/m104)
__device__ __forceinline__ void glds16(const __bf16* g, __bf16* l) {
    __builtin_amdgcn_global_load_lds((const __attribute__((address_space(1))) void*)g,
                                     (__attribute__((address_space(3))) void*)l, 16, 0, 0);
}

// ---------------- f32 -> bf16 conversion, zero-padded K tail; visit + alpha fused ----------------
__global__ __launch_bounds__(256) void k_cvt2(const float* __restrict__ visit,
                                              const float* __restrict__ alpha_w,
                                              __bf16* __restrict__ visit_bf,
                                              __bf16* __restrict__ alpha_bf) {
    long bid = blockIdx.x;
    const float* ip; __bf16* op;
    if (bid < BV*VV) { ip = visit + bid*4000; op = visit_bf + bid*AK; }
    else             { long r = bid - BV*VV; ip = alpha_w + r*4000; op = alpha_bf + r*AK; }
    int t = threadIdx.x;
    if (t < 250) {
        const float4* p4 = (const float4*)ip + t*4;
        float4 f0 = p4[0], f1 = p4[1], f2 = p4[2], f3 = p4[3];
        bf16x8 h0, h1;
        h0[0]=(__bf16)f0.x; h0[1]=(__bf16)f0.y; h0[2]=(__bf16)f0.z; h0[3]=(__bf16)f0.w;
        h0[4]=(__bf16)f1.x; h0[5]=(__bf16)f1.y; h0[6]=(__bf16)f1.z; h0[7]=(__bf16)f1.w;
        h1[0]=(__bf16)f2.x; h1[1]=(__bf16)f2.y; h1[2]=(__bf16)f2.z; h1[3]=(__bf16)f2.w;
        h1[4]=(__bf16)f3.x; h1[5]=(__bf16)f3.y; h1[6]=(__bf16)f3.z; h1[7]=(__bf16)f3.w;
        ((bf16x8*)op)[t*2]   = h0;
        ((bf16x8*)op)[t*2+1] = h1;
    } else if (t < 254) {
        bf16x8 zz;
        #pragma unroll
        for (int j = 0; j < 8; j++) zz[j] = (__bf16)0.f;
        ((bf16x8*)op)[500 + (t - 250)] = zz;
    }
}

// ---------------- alpha GEMM: z[l,row,col] = visit[row,:] . alpha_w[l][col,:] ----------------
// bf16 in (stride AK), BK=64 glds16 staging, XOR-swizzled LDS (0 bank conflicts, R5),
// XCD-grouped swizzle (R3), split-K=4 with bf16 partial stores (R6).
__global__ __launch_bounds__(256)
void gemm_alpha(const __bf16* __restrict__ visit_bf, const __bf16* __restrict__ alpha_bf,
                __bf16* __restrict__ zpart)
{
    __shared__ __bf16 Ah[128*64];   // granule g of row r at r*64 + (g^(r&7))*8
    __shared__ __bf16 Bh[128*64];

    const int id   = blockIdx.x;      // 0..1919
    const int xcd  = id & 7;
    const int slot = id >> 3;         // 0..239
    const int mi   = slot % 5;        // 0..4
    const int gix  = slot / 5;        // 0..47
    const int g    = xcd * 48 + gix;  // 0..383
    const int ni   = g & 31;          // 0..31
    const int lkh  = g >> 5;          // 0..11
    const int l    = lkh >> 2;        // 0..2
    const int kh   = lkh & 3;         // 0..3

    const __bf16* Ag = visit_bf;
    const __bf16* Bg = alpha_bf + (long)l * NNODES * AK;
    __bf16*       Cg = zpart + (long)kh * ZSTRIDE + (long)l * 640 * 4000;
    const int m0 = mi * 128;
    const int n0 = ni * 128;
    const int k0 = kh * 1024;
    const int k1 = (kh == 3) ? AK : (k0 + 1024);

    const int tid = threadIdx.x;
    const int wv  = tid >> 6;
    const int ln  = tid & 63;
    const int srow = ln >> 3;
    const int gsl  = (ln & 7) ^ srow;

    const __bf16* aA = Ag + (long)(m0 + wv*8 + srow) * AK + gsl*8;
    const __bf16* bB[4];
    #pragma unroll
    for (int t = 0; t < 4; t++) {
        int br = n0 + wv*8 + srow + t*32;
        if (br > NNODES-1) br = NNODES-1;      // clamp (cols>=4000 masked at store)
        bB[t] = Bg + (long)br * AK + gsl*8;
    }

    const int wm = (wv & 1) * 64;
    const int wn = (wv >> 1) * 64;
    const int lr = ln & 15;
    const int kq = ln >> 4;
    const int sw0 = lr & 7;

    f32x4 acc[4][4];
    #pragma unroll
    for (int i = 0; i < 4; i++)
        #pragma unroll
        for (int j = 0; j < 4; j++)
            acc[i][j] = (f32x4){0.f, 0.f, 0.f, 0.f};

    for (int kb = k0; kb < k1; kb += 64) {
        #pragma unroll
        for (int t = 0; t < 4; t++) {
            glds16(aA + (long)t*32*AK + kb, &Ah[(t*4 + wv) * 512]);
            glds16(bB[t] + kb,              &Bh[(t*4 + wv) * 512]);
        }
        __syncthreads();
        #pragma unroll
        for (int ks = 0; ks < 2; ks++) {
            const int sg = ((ks*4 + kq) ^ sw0) * 8;
            bf16x8 af[4], bfr[4];
            #pragma unroll
            for (int i = 0; i < 4; i++) {
                af[i]  = *(const bf16x8*)&Ah[(wm + i*16 + lr)*64 + sg];
                bfr[i] = *(const bf16x8*)&Bh[(wn + i*16 + lr)*64 + sg];
            }
            #pragma unroll
            for (int i = 0; i < 4; i++)
                #pragma unroll
                for (int j = 0; j < 4; j++)
                    acc[i][j] = __builtin_amdgcn_mfma_f32_16x16x32_bf16(af[i], bfr[j], acc[i][j], 0, 0, 0);
        }
        __syncthreads();
    }

    // C/D layout col=lane&15, row=(lane>>4)*4+reg (m89/m91-verified)
    #pragma unroll
    for (int i = 0; i < 4; i++) {
        const int row_b = m0 + wm + i*16 + kq*4;   // < 640 always
        #pragma unroll
        for (int j = 0; j < 4; j++) {
            const int col = n0 + wn + j*16 + lr;
            if (col < NNODES) {
                #pragma unroll
                for (int r = 0; r < 4; r++)
                    Cg[(long)(row_b + r)*4000 + col] = (__bf16)acc[i][j][r];
            }
        }
    }
}

// ---------------- generic small GEMM (C = A * B^T), split-bf16 for ~f32 accuracy ----------------
#define BM 128
#define BN 128
#define BKG 32
#define LSTR 40

template<int SPLIT>
__device__ __forceinline__ void stage_tile(const float* __restrict__ G, int rows, int Kdim,
                                           int r0, int kb, int k1, __bf16* Sh, __bf16* Sl, int tid)
{
    const int sr  = tid >> 1;
    const int skc = (tid & 1) * 16;
    const int gr  = r0 + sr;
    const int gk  = kb + skc;
    float va[16];
    if (gr < rows && gk + 16 <= k1) {
        const float4* p4 = (const float4*)(G + (long)gr * Kdim + gk);
        #pragma unroll
        for (int q = 0; q < 4; q++) {
            float4 f = p4[q];
            va[4*q+0] = f.x; va[4*q+1] = f.y; va[4*q+2] = f.z; va[4*q+3] = f.w;
        }
    } else {
        #pragma unroll
        for (int j = 0; j < 16; j++) {
            int kk = gk + j;
            va[j] = (gr < rows && kk < k1) ? G[(long)gr * Kdim + kk] : 0.0f;
        }
    }
    bf16x8 h[2], lo[2];
    #pragma unroll
    for (int half = 0; half < 2; half++) {
        #pragma unroll
        for (int j = 0; j < 8; j++) {
            float v = va[half*8 + j];
            __bf16 hi = (__bf16)v;
            h[half][j]  = hi;
            lo[half][j] = (__bf16)(v - (float)hi);
        }
    }
    *(bf16x8*)&Sh[sr*LSTR + skc]     = h[0];
    *(bf16x8*)&Sh[sr*LSTR + skc + 8] = h[1];
    if (SPLIT) {
        *(bf16x8*)&Sl[sr*LSTR + skc]     = lo[0];
        *(bf16x8*)&Sl[sr*LSTR + skc + 8] = lo[1];
    }
}

template<int SPLIT, int RELU, int BIAS, int WRITEB>
__global__ __launch_bounds__(256)
void gemm_bt(const float* __restrict__ Ag, const float* __restrict__ Bg,
             float* __restrict__ Cg, const float* __restrict__ bias,
             __bf16* __restrict__ Xb, int M, int N, int K)
{
    __shared__ __bf16 Ah[BM*LSTR];
    __shared__ __bf16 Bh[BN*LSTR];
    __shared__ __bf16 Alo[SPLIT ? BM*LSTR : 1];
    __shared__ __bf16 Blo[SPLIT ? BN*LSTR : 1];

    const int tid = threadIdx.x;
    const int m0 = blockIdx.x * BM;
    const int n0 = blockIdx.y * BN;

    const int wave = tid >> 6;
    const int lane = tid & 63;
    const int wm = (wave & 1) * 64;
    const int wn = (wave >> 1) * 64;
    const int lr = lane & 15;
    const int kq = lane >> 4;

    f32x4 acc[4][4];
    #pragma unroll
    for (int i = 0; i < 4; i++)
        #pragma unroll
        for (int j = 0; j < 4; j++)
            acc[i][j] = (f32x4){0.f, 0.f, 0.f, 0.f};

    for (int kb = 0; kb < K; kb += BKG) {
        stage_tile<SPLIT>(Ag, M, K, m0, kb, K, Ah, Alo, tid);
        stage_tile<SPLIT>(Bg, N, K, n0, kb, K, Bh, Blo, tid);
        __syncthreads();

        bf16x8 af[4], bfr[4];
        #pragma unroll
        for (int i = 0; i < 4; i++) {
            af[i]  = *(const bf16x8*)&Ah[(wm + i*16 + lr)*LSTR + kq*8];
            bfr[i] = *(const bf16x8*)&Bh[(wn + i*16 + lr)*LSTR + kq*8];
        }
        #pragma unroll
        for (int i = 0; i < 4; i++)
            #pragma unroll
            for (int j = 0; j < 4; j++)
                acc[i][j] = __builtin_amdgcn_mfma_f32_16x16x32_bf16(af[i], bfr[j], acc[i][j], 0, 0, 0);

        if (SPLIT) {
            bf16x8 al[4], bl[4];
            #pragma unroll
            for (int i = 0; i < 4; i++) {
                al[i] = *(const bf16x8*)&Alo[(wm + i*16 + lr)*LSTR + kq*8];
                bl[i] = *(const bf16x8*)&Blo[(wn + i*16 + lr)*LSTR + kq*8];
            }
            #pragma unroll
            for (int i = 0; i < 4; i++)
                #pragma unroll
                for (int j = 0; j < 4; j++) {
                    acc[i][j] = __builtin_amdgcn_mfma_f32_16x16x32_bf16(af[i], bl[j], acc[i][j], 0, 0, 0);
                    acc[i][j] = __builtin_amdgcn_mfma_f32_16x16x32_bf16(al[i], bfr[j], acc[i][j], 0, 0, 0);
                }
        }
        __syncthreads();
    }

    #pragma unroll
    for (int i = 0; i < 4; i++) {
        const int row_b = m0 + wm + i*16 + kq*4;
        #pragma unroll
        for (int j = 0; j < 4; j++) {
            const int col = n0 + wn + j*16 + lr;
            if (col < N) {
                #pragma unroll
                for (int r = 0; r < 4; r++) {
                    const int row = row_b + r;
                    if (row < M) {
                        float v = acc[i][j][r];
                        if (BIAS) v += bias[col];
                        if (RELU) v = fmaxf(v, 0.0f);
                        Cg[(long)row*N + col] = v;
                        if (WRITEB) Xb[(long)row*N + col] = (__bf16)v;
                    }
                }
            }
        }
    }
}

// ---------------- CSR build (parallel scan: R7, replaces 110us single-block k_scan) ----------------
__global__ void k_count(const int* __restrict__ dst, int* __restrict__ deg) {
    int e = blockIdx.x*256 + threadIdx.x;
    if (e < WS_E) atomicAdd(&deg[dst[e]], 1);
}

// per-block sum of 256 degrees -> bsum[block]
__global__ __launch_bounds__(256) void k_scan1(const int* __restrict__ deg, int* __restrict__ bsum) {
    __shared__ int red[256];
    int t = threadIdx.x;
    int i = blockIdx.x*256 + t;
    red[t] = (i < WS_N) ? deg[i] : 0;
    __syncthreads();
    for (int o = 128; o > 0; o >>= 1) {
        if (t < o) red[t] += red[t + o];
        __syncthreads();
    }
    if (t == 0) bsum[blockIdx.x] = red[0];
}

// exclusive scan of SCAN_NB block sums (single 256-thread block)
__global__ __launch_bounds__(256) void k_scan2(const int* __restrict__ bsum, int* __restrict__ bbase,
                                               int* __restrict__ offs) {
    __shared__ int s[256];
    int t = threadIdx.x;
    int v = (t < SCAN_NB) ? bsum[t] : 0;
    s[t] = v;
    __syncthreads();
    for (int o = 1; o < 256; o <<= 1) {
        int add = (t >= o) ? s[t - o] : 0;
        __syncthreads();
        s[t] += add;
        __syncthreads();
    }
    if (t < SCAN_NB) bbase[t] = s[t] - v;   // exclusive
    if (t == 0) offs[WS_N] = WS_E;
}

// local exclusive scan + block base -> offs, cursor
__global__ __launch_bounds__(256) void k_scan3(const int* __restrict__ deg, const int* __restrict__ bbase,
                                               int* __restrict__ offs, int* __restrict__ cursor) {
    __shared__ int s[256];
    int t = threadIdx.x;
    int i = blockIdx.x*256 + t;
    int v = (i < WS_N) ? deg[i] : 0;
    s[t] = v;
    __syncthreads();
    for (int o = 1; o < 256; o <<= 1) {
        int add = (t >= o) ? s[t - o] : 0;
        __syncthreads();
        s[t] += add;
        __syncthreads();
    }
    if (i < WS_N) {
        int e = bbase[blockIdx.x] + s[t] - v;
        offs[i] = e;
        cursor[i] = e;
    }
}

__global__ void k_fill(const int* __restrict__ dst, const int* __restrict__ src,
                       const int* __restrict__ rel, int* __restrict__ cursor,
                       int2* __restrict__ sr) {
    int e = blockIdx.x*256 + threadIdx.x;
    if (e < WS_E) {
        int d = dst[e];
        int p = atomicAdd(&cursor[d], 1);
        sr[p] = make_int2(src[e], rel[e]);
    }
}

// ---------------- small precompute kernels ----------------
__global__ __launch_bounds__(128) void k_relmsg(const float* __restrict__ Wrel, const float* __restrict__ wr_w,
                                                const float* __restrict__ wr_b, __bf16* __restrict__ relmsg) {
    int l = blockIdx.x / NRELS;
    int r = blockIdx.x % NRELS;
    int o = threadIdx.x;
    float wv = Wrel[r*HIDD + o];
    __shared__ float red[128];
    red[o] = wv * wr_w[l*HIDD + o];
    __syncthreads();
    for (int s = 64; s > 0; s >>= 1) {
        if (o < s) red[o] += red[o + s];
        __syncthreads();
    }
    float wrel = red[0] + wr_b[l];
    relmsg[((long)l*NRELS + r)*HIDD + o] = (__bf16)(wrel * wv);
}

// x init + bf16 shadow + per-layer node attention gather (fused)
__global__ void k_xinit(const float* __restrict__ Wnode, const int* __restrict__ nid,
                        const int* __restrict__ batch, const float* __restrict__ attn,
                        float* __restrict__ x, __bf16* __restrict__ xb, float* __restrict__ an) {
    int t = blockIdx.x*256 + threadIdx.x;
    if (t >= WS_N*32) return;
    int i = t >> 5;
    int d = t & 31;
    int n = nid[i];
    float4 v = ((const float4*)Wnode)[n*32 + d];
    ((float4*)x)[i*32 + d] = v;
    bf16x4 b;
    b[0] = (__bf16)v.x; b[1] = (__bf16)v.y; b[2] = (__bf16)v.z; b[3] = (__bf16)v.w;
    ((bf16x4*)xb)[i*32 + d] = b;
    if (d < LL) an[(long)d*WS_N + i] = attn[((long)d*BV + batch[i]) * NNODES + n];
}

__global__ __launch_bounds__(256) void k_beta(const float* __restrict__ visit, const float* __restrict__ beta_w,
                                              const float* __restrict__ beta_b, float* __restrict__ beta) {
    int id = blockIdx.x;
    int l = id / (BV*VV);
    int rem = id % (BV*VV);
    int b = rem / VV;
    int v = rem % VV;
    const float* row = visit + ((long)b*VV + v) * NNODES;
    const float* wr  = beta_w + (long)l * NNODES;
    float s = 0.f;
    for (int n = threadIdx.x; n < NNODES; n += 256) s += row[n] * wr[n];
    __shared__ float red[256];
    red[threadIdx.x] = s; __syncthreads();
    for (int o = 128; o > 0; o >>= 1) {
        if (threadIdx.x < o) red[threadIdx.x] += red[threadIdx.x + o];
        __syncthreads();
    }
    if (threadIdx.x == 0) {
        float lam = __expf(DECAYF * (float)(VV - v));
        beta[id] = tanhf(red[0] + beta_b[l]) * lam;
    }
}

// softmax over v + beta-weighted pool; sums the 4 bf16 split-K partials inline
__global__ __launch_bounds__(256) void k_attnpool(const __bf16* __restrict__ zpart,
                                                  const float* __restrict__ beta, float* __restrict__ attn) {
    int m = blockIdx.x*256 + threadIdx.x;
    int b = blockIdx.y;
    int l = blockIdx.z;
    if (m >= NNODES) return;
    const __bf16* zp = zpart + ((long)l*640 + b*VV) * 4000 + m;
    const float* bet = beta + (l*BV + b) * VV;
    float zv[VV];
    float mx = -1e30f;
    #pragma unroll
    for (int v = 0; v < VV; v++) {
        long o = (long)v * 4000;
        float s = (float)zp[o] + (float)zp[ZSTRIDE + o] + (float)zp[2*ZSTRIDE + o] + (float)zp[3*ZSTRIDE + o];
        zv[v] = s;
        mx = fmaxf(mx, s);
    }
    float s = 0.f, ws = 0.f;
    #pragma unroll
    for (int v = 0; v < VV; v++) {
        float e = __expf(zv[v] - mx);
        s += e;
        ws += e * bet[v];
    }
    attn[((long)l*BV + b) * NNODES + m] = ws / s;
}

// ---------------- message + aggregate (R5 form: wave per dst node, 8-edge unroll) ----------------
__global__ __launch_bounds__(256) void k_agg(const float* __restrict__ x, const __bf16* __restrict__ xb,
                                             const float* __restrict__ an,
                                             const __bf16* __restrict__ relmsg_l, const int* __restrict__ offs,
                                             const int2* __restrict__ sr,
                                             float* __restrict__ outb) {
    int node = blockIdx.x*4 + (threadIdx.x >> 6);
    int lane = threadIdx.x & 63;
    if (node >= WS_N) return;
    int e0 = offs[node], e1 = offs[node + 1];
    const bf16x2* xb2 = (const bf16x2*)xb;
    const bf16x2* rm2 = (const bf16x2*)relmsg_l;
    float2 acc = {0.f, 0.f};
    int e = e0;
    for (; e + 8 <= e1; e += 8) {
        int2 p[8];
        #pragma unroll
        for (int q = 0; q < 8; q++) p[q] = sr[e + q];
        float a[8]; bf16x2 gv[8], mv[8];
        #pragma unroll
        for (int q = 0; q < 8; q++) a[q] = an[p[q].x];
        #pragma unroll
        for (int q = 0; q < 8; q++) gv[q] = xb2[p[q].x*64 + lane];
        #pragma unroll
        for (int q = 0; q < 8; q++) mv[q] = rm2[p[q].y*64 + lane];
        #pragma unroll
        for (int q = 0; q < 8; q++) {
            acc.x += fmaxf((float)gv[q][0]*a[q] + (float)mv[q][0], 0.f);
            acc.y += fmaxf((float)gv[q][1]*a[q] + (float)mv[q][1], 0.f);
        }
    }
    for (; e < e1; e++) {
        int2 pa = sr[e];
        float aa = an[pa.x];
        bf16x2 ga = xb2[pa.x*64 + lane];
        bf16x2 va = rm2[pa.y*64 + lane];
        acc.x += fmaxf((float)ga[0]*aa + (float)va[0], 0.f);
        acc.y += fmaxf((float)ga[1]*aa + (float)va[1], 0.f);
    }
    float2 xo = ((const float2*)x)[node*64 + lane];
    acc.x += xo.x; acc.y += xo.y;
    ((float2*)outb)[node*64 + lane] = acc;
}

// ---------------- pooling partials ----------------
__global__ __launch_bounds__(256) void k_pool_partial(const float* __restrict__ x,
                                                      const int* __restrict__ batch,
                                                      float* __restrict__ xgsum) {
    int r0 = blockIdx.x * 128;
    int d = threadIdx.x & 127;
    int rofs = threadIdx.x >> 7;
    int r1 = min(r0 + 128, WS_N);
    float acc = 0.f;
    int curb = -1;
    for (int i = r0 + rofs; i < r1; i += 2) {
        int b = batch[i];
        if (b != curb) {
            if (curb >= 0) atomicAdd(&xgsum[curb*HIDD + d], acc);
            acc = 0.f; curb = b;
        }
        acc += x[(long)i*HIDD + d];
    }
    if (curb >= 0) atomicAdd(&xgsum[curb*HIDD + d], acc);
}

__global__ __launch_bounds__(128) void k_ehrpool(const float* __restrict__ ehr,
                                                 const float* __restrict__ node_emb,
                                                 float* __restrict__ xnsum, float* __restrict__ esum) {
    int b = blockIdx.y;
    int c = blockIdx.x;
    int d = threadIdx.x;
    int n0 = c * (NNODES/16), n1 = n0 + (NNODES/16);
    float acc = 0.f;
    for (int n = n0; n < n1; n++) {
        acc += ehr[b*NNODES + n] * node_emb[(long)n*HIDD + d];
    }
    atomicAdd(&xnsum[b*HIDD + d], acc);
    float s = 0.f;
    for (int n = n0 + d; n < n1; n += 128) s += ehr[b*NNODES + n];
    __shared__ float red[128];
    red[d] = s; __syncthreads();
    for (int o = 64; o > 0; o >>= 1) {
        if (d < o) red[d] += red[d + o];
        __syncthreads();
    }
    if (d == 0) atomicAdd(&esum[b], red[0]);
}

// fused head: batch-count (binary search) + mean + x_node linear + concat + mlp
__global__ __launch_bounds__(128) void k_head(const float* __restrict__ xgsum,
                                              const float* __restrict__ xnsum,
                                              const float* __restrict__ esum,
                                              const int* __restrict__ batch,
                                              const float* __restrict__ lin_w, const float* __restrict__ lin_b,
                                              const float* __restrict__ mlp_w, const float* __restrict__ mlp_b,
                                              float* __restrict__ out) {
    int b = blockIdx.x;
    int d = threadIdx.x;
    int lo = 0, hi = WS_N;
    while (lo < hi) { int mid = (lo + hi) >> 1; if (batch[mid] < b) lo = mid + 1; else hi = mid; }
    int s0 = lo;
    lo = 0; hi = WS_N;
    while (lo < hi) { int mid = (lo + hi) >> 1; if (batch[mid] < b + 1) lo = mid + 1; else hi = mid; }
    int cnt = max(lo - s0, 1);
    __shared__ float t1[128];
    __shared__ float cat[2*HIDD];
    t1[d]  = xnsum[b*HIDD + d] / esum[b];
    cat[d] = xgsum[b*HIDD + d] / (float)cnt;
    __syncthreads();
    float o2 = lin_b[d];
    for (int k2 = 0; k2 < HIDD; k2++) o2 += t1[k2] * lin_w[d*HIDD + k2];
    cat[HIDD + d] = o2;
    __syncthreads();
    if (d < OUTD) {
        float a = mlp_b[d];
        for (int j = 0; j < 2*HIDD; j++) a += cat[j] * mlp_w[d*2*HIDD + j];
        out[b*OUTD + d] = a;
    }
}

// ---------------- launcher ----------------
extern "C" void kernel_launch(void* const* d_in, const int* in_sizes, int n_in,
                              void* d_out, int out_size, void* d_ws, size_t ws_size,
                              hipStream_t stream)
{
    const float* node_emb = (const float*)d_in[0];
    const float* rel_emb  = (const float*)d_in[1];
    const float* lin_w    = (const float*)d_in[2];
    const float* lin_b    = (const float*)d_in[3];
    const float* alpha_w  = (const float*)d_in[4];
    // d_in[5] alpha_b: shift-invariant under softmax over v -> unused
    const float* beta_w   = (const float*)d_in[6];
    const float* beta_b   = (const float*)d_in[7];
    const float* wr_w     = (const float*)d_in[8];
    const float* wr_b     = (const float*)d_in[9];
    const float* conv_w   = (const float*)d_in[10];
    const float* conv_b   = (const float*)d_in[11];
    const float* mlp_w    = (const float*)d_in[12];
    const float* mlp_b    = (const float*)d_in[13];
    const float* visit    = (const float*)d_in[14];
    const float* ehr      = (const float*)d_in[15];
    const int* node_ids   = (const int*)d_in[16];
    const int* rel_ids    = (const int*)d_in[17];
    const int* ei         = (const int*)d_in[18];
    const int* batch      = (const int*)d_in[19];
    const int* esrc = ei;
    const int* edst = ei + WS_E;
    float* out = (float*)d_out;

    char* p = (char*)d_ws;
    auto take = [&](size_t bytes) -> char* {
        char* q = p;
        p += (bytes + 255) & ~(size_t)255;
        return q;
    };
    __bf16* zpart    = (__bf16*)take((size_t)4*ZSTRIDE*2);        // 61.4 MB: 4 bf16 split-K partials (aggbuf later)
    __bf16* visit_bf = (__bf16*)take((size_t)(BV*VV)*AK*2);       // 5.2 MB
    char*   big      = take((size_t)LL*NNODES*AK*2);              // 96.8 MB: alpha_bf, then carved
    float* betab  = (float*)take((size_t)LL*BV*VV*4);
    float* xgsum  = (float*)take((size_t)BV*HIDD*4);
    float* xnsum  = (float*)take((size_t)BV*HIDD*4);
    float* esum   = (float*)take((size_t)BV*4);
    size_t small_zero_bytes = (size_t)((char*)(esum + BV) - (char*)xgsum);
    int* deg      = (int*)take((size_t)WS_N*4);
    int* offs     = (int*)take((size_t)(WS_N+1)*4);
    int* cursor   = (int*)take((size_t)WS_N*4);
    int* bsum     = (int*)take((size_t)SCAN_NB*4);
    int* bbase    = (int*)take((size_t)SCAN_NB*4);
    if ((size_t)(p - (char*)d_ws) > ws_size) return;  // ws too small: leave output poisoned (visible failure)

    // alpha_bf occupies `big` during cvt+gemm_alpha; afterwards carved (stream-ordered -> safe):
    __bf16* alpha_bf = (__bf16*)big;
    char* q = big;
    auto carve = [&](size_t bytes) -> char* {
        char* r = q;
        q += (bytes + 255) & ~(size_t)255;
        return r;
    };
    float*  x      = (float*)carve((size_t)WS_N*HIDD*4);     // 25.6 MB
    __bf16* xb     = (__bf16*)carve((size_t)WS_N*HIDD*2);    // 12.8 MB
    int2*   sr     = (int2*)carve((size_t)WS_E*8);           // 6.4 MB
    float*  attn   = (float*)carve((size_t)LL*BV*NNODES*4);  // 1.5 MB (written by attnpool AFTER gemm_alpha)
    float*  attnnd = (float*)carve((size_t)LL*WS_N*4);       // 0.6 MB
    float*  Wnode  = (float*)carve((size_t)NNODES*HIDD*4);   // 2.0 MB
    float*  Wrel   = (float*)carve((size_t)NRELS*HIDD*4);
    __bf16* relmsg = (__bf16*)carve((size_t)LL*NRELS*HIDD*2);
    float*  aggbuf = (float*)zpart;                          // zpart dead after attnpool

    (void)hipMemsetAsync(deg, 0, (size_t)WS_N*4, stream);
    (void)hipMemsetAsync(xgsum, 0, small_zero_bytes, stream);

    // ---- phase 1: alpha attention ----
    k_cvt2<<<dim3(BV*VV + LL*NNODES), 256, 0, stream>>>(visit, alpha_w, visit_bf, alpha_bf);
    gemm_alpha<<<dim3(1920), 256, 0, stream>>>(visit_bf, alpha_bf, zpart);
    k_beta<<<dim3(LL*BV*VV), 256, 0, stream>>>(visit, beta_w, beta_b, betab);
    k_attnpool<<<dim3((NNODES+255)/256, BV, LL), 256, 0, stream>>>(zpart, betab, attn);

    // ---- phase 2: graph features (carved from the now-dead alpha_bf region) ----
    k_count<<<dim3((WS_E+255)/256), 256, 0, stream>>>(edst, deg);
    k_scan1<<<dim3(SCAN_NB), 256, 0, stream>>>(deg, bsum);
    k_scan2<<<1, 256, 0, stream>>>(bsum, bbase, offs);
    k_scan3<<<dim3(SCAN_NB), 256, 0, stream>>>(deg, bbase, offs, cursor);
    k_fill<<<dim3((WS_E+255)/256), 256, 0, stream>>>(edst, esrc, rel_ids, cursor, sr);

    gemm_bt<1,0,1,0><<<dim3((NNODES+BM-1)/BM, 1, 1), 256, 0, stream>>>(
        node_emb, lin_w, Wnode, lin_b, nullptr, NNODES, HIDD, HIDD);
    gemm_bt<1,0,1,0><<<dim3((NRELS+BM-1)/BM, 1, 1), 256, 0, stream>>>(
        rel_emb, lin_w, Wrel, lin_b, nullptr, NRELS, HIDD, HIDD);
    k_relmsg<<<dim3(LL*NRELS), 128, 0, stream>>>(Wrel, wr_w, wr_b, relmsg);
    k_xinit<<<dim3((WS_N*32+255)/256), 256, 0, stream>>>(Wnode, node_ids, batch, attn, x, xb, attnnd);

    // ---- phase 3: GNN layers ----
    for (int l = 0; l < LL; l++) {
        k_agg<<<dim3((WS_N+3)/4), 256, 0, stream>>>(
            x, xb, attnnd + (size_t)l*WS_N, relmsg + (size_t)l*NRELS*HIDD, offs, sr, aggbuf);
        gemm_bt<1,1,1,1><<<dim3((WS_N+BM-1)/BM, 1, 1), 256, 0, stream>>>(
            aggbuf, conv_w + (size_t)l*HIDD*HIDD, x, conv_b + (size_t)l*HIDD, xb,
            WS_N, HIDD, HIDD);
    }

    // ---- phase 4: pooling + head ----
    k_pool_partial<<<dim3((WS_N+127)/128), 256, 0, stream>>>(x, batch, xgsum);
    k_ehrpool<<<dim3(16, BV), 128, 0, stream>>>(ehr, node_emb, xnsum, esum);
    k_head<<<BV, 128, 0, stream>>>(xgsum, xnsum, esum, batch, lin_w, lin_b, mlp_w, mlp_b, out);
}